// Round 1
// baseline (967.278 us; speedup 1.0000x reference)
//
#include <hip/hip_runtime.h>
#include <hip/hip_bf16.h>
#include <stdint.h>

// PerceiverProjector on MI355X, restructured as 5 bf16 MFMA GEMMs:
//  Ut = (q*SCALE) @ W_k^T per head          [1024,1024]   0.5 GF
//  St[b] = Ut @ vit[b]^T                    [b][hq][n]   68.7 GF
//  P = softmax rows of St                   (n contiguous)
//  vT[b] = Wv^T @ vit[b]^T                  [b][d][n]   275 GF
//  attn_out[b,h] = P_bh @ vT_bh^T           [2048,4096]  34 GF
//  out = attn_out @ W_o                     fp32         68.7 GF

typedef unsigned short u16;
typedef long long ll;
typedef __attribute__((ext_vector_type(8))) __bf16 bf16x8;
typedef __attribute__((ext_vector_type(4))) float f32x4;

#define AS1 __attribute__((address_space(1)))
#define AS3 __attribute__((address_space(3)))

__device__ __forceinline__ u16 f2bf(float f) {
  unsigned u = __builtin_bit_cast(unsigned, f);
  return (u16)((u + 0x7FFFu + ((u >> 16) & 1u)) >> 16);  // RNE
}
__device__ __forceinline__ float bf2f(u16 b) {
  return __builtin_bit_cast(float, ((unsigned)b) << 16);
}
__device__ __forceinline__ void st_c(float* p, float v) { *p = v; }
__device__ __forceinline__ void st_c(u16* p, float v) { *p = f2bf(v); }

// async global->LDS, 16B per lane; LDS dest must be wave-uniform base (+lane*16 HW-applied)
__device__ __forceinline__ void gload16(const u16* g, u16* l) {
  __builtin_amdgcn_global_load_lds((AS1 void*)(uintptr_t)g,
                                   (AS3 void*)(unsigned)(uintptr_t)l, 16, 0, 0);
}

// C[m][n] = sum_k A[m][k] * Bt[n][k]; 128x128 tile, BK=64, 4 waves (2x2), m97 structure.
// batch z -> (b1 = z/nb2, b2 = z%nb2); strides in elements.
template <typename CT>
__global__ __launch_bounds__(256, 2) void gemm_bt(
    const u16* __restrict__ A, const u16* __restrict__ Bt, CT* __restrict__ C,
    int M, int N, int K, int lda, int ldb, int ldc, int nb2,
    ll sA1, ll sA2, ll sB1, ll sB2, ll sC1, ll sC2)
{
  __shared__ __align__(16) u16 As[128 * 64];
  __shared__ __align__(16) u16 Bs[128 * 64];

  const int z = blockIdx.z;
  const int b1 = z / nb2, b2 = z - b1 * nb2;
  A += b1 * sA1 + b2 * sA2;
  Bt += b1 * sB1 + b2 * sB2;
  C += b1 * sC1 + b2 * sC2;

  const int m0 = blockIdx.y * 128;
  const int n0 = blockIdx.x * 128;
  const int tid = threadIdx.x;
  const int lane = tid & 63;
  const int wave = tid >> 6;

  const int srow = lane >> 3;        // 0..7 within an 8-row 1KB chunk
  const int scol = (lane & 7) << 3;  // bf16 col, 16B per lane
  const int wr = (wave >> 1) << 6;   // wave row offset 0/64
  const int wc = (wave & 1) << 6;    // wave col offset 0/64
  const int lrow = lane & 15;
  const int lk = (lane >> 4) << 3;   // per-lane k offset 0/8/16/24

  f32x4 acc[4][4];
#pragma unroll
  for (int i = 0; i < 4; ++i)
#pragma unroll
    for (int j = 0; j < 4; ++j) { f32x4 zz = {0.f, 0.f, 0.f, 0.f}; acc[i][j] = zz; }

  for (int k0 = 0; k0 < K; k0 += 64) {
#pragma unroll
    for (int i = 0; i < 4; ++i) {               // stage A tile 128x64 (16KB)
      int chunk = (i << 2) + wave;
      int row = (chunk << 3) + srow;
      int gr = m0 + row; gr = gr < M ? gr : M - 1;   // clamp (stores guarded)
      gload16(A + (size_t)gr * lda + k0 + scol, &As[chunk << 9]);
    }
#pragma unroll
    for (int i = 0; i < 4; ++i) {               // stage Bt tile 128x64
      int chunk = (i << 2) + wave;
      int row = (chunk << 3) + srow;
      int gc = n0 + row; gc = gc < N ? gc : N - 1;
      gload16(Bt + (size_t)gc * ldb + k0 + scol, &Bs[chunk << 9]);
    }
    __syncthreads();  // compiler drains vmcnt before barrier
#pragma unroll
    for (int ks = 0; ks < 64; ks += 32) {
      bf16x8 af[4], bfr[4];
#pragma unroll
      for (int mi = 0; mi < 4; ++mi)
        af[mi] = *(const bf16x8*)&As[((wr + (mi << 4) + lrow) << 6) + ks + lk];
#pragma unroll
      for (int ni = 0; ni < 4; ++ni)
        bfr[ni] = *(const bf16x8*)&Bs[((wc + (ni << 4) + lrow) << 6) + ks + lk];
#pragma unroll
      for (int mi = 0; mi < 4; ++mi)
#pragma unroll
        for (int ni = 0; ni < 4; ++ni)
          acc[mi][ni] = __builtin_amdgcn_mfma_f32_16x16x32_bf16(af[mi], bfr[ni], acc[mi][ni], 0, 0, 0);
    }
    __syncthreads();
  }

  const int rbase = m0 + wr + ((lane >> 4) << 2);
  const int cbase = n0 + wc + lrow;
#pragma unroll
  for (int mi = 0; mi < 4; ++mi)
#pragma unroll
    for (int r = 0; r < 4; ++r) {
      int row = rbase + (mi << 4) + r;
      if (row < M) {
#pragma unroll
        for (int ni = 0; ni < 4; ++ni) {
          int col = cbase + (ni << 4);
          if (col < N) st_c(&C[(size_t)row * ldc + col], acc[mi][ni][r]);
        }
      }
    }
}

// one block per row of 1024 bf16 logits -> normalized bf16 probs
__global__ __launch_bounds__(256) void softmax_rows(const u16* __restrict__ S, u16* __restrict__ P) {
  __shared__ float red[8];
  size_t row = blockIdx.x;
  const u16* s = S + row * 1024;
  u16* p = P + row * 1024;
  int t = threadIdx.x;
  ushort4 ld = ((const ushort4*)s)[t];
  float v0 = bf2f(ld.x), v1 = bf2f(ld.y), v2 = bf2f(ld.z), v3 = bf2f(ld.w);
  float m = fmaxf(fmaxf(v0, v1), fmaxf(v2, v3));
#pragma unroll
  for (int o = 32; o; o >>= 1) m = fmaxf(m, __shfl_xor(m, o));
  if ((t & 63) == 0) red[t >> 6] = m;
  __syncthreads();
  m = fmaxf(fmaxf(red[0], red[1]), fmaxf(red[2], red[3]));
  float e0 = __expf(v0 - m), e1 = __expf(v1 - m), e2 = __expf(v2 - m), e3 = __expf(v3 - m);
  float sum = (e0 + e1) + (e2 + e3);
#pragma unroll
  for (int o = 32; o; o >>= 1) sum += __shfl_xor(sum, o);
  if ((t & 63) == 0) red[4 + (t >> 6)] = sum;
  __syncthreads();
  sum = (red[4] + red[5]) + (red[6] + red[7]);
  float rs = 1.0f / (sum + 1e-9f);
  ushort4 o4;
  o4.x = f2bf(e0 * rs); o4.y = f2bf(e1 * rs); o4.z = f2bf(e2 * rs); o4.w = f2bf(e3 * rs);
  ((ushort4*)p)[t] = o4;
}

// contiguous fp32 -> bf16 cast (xscale), float4 vectorized, grid-stride
__global__ __launch_bounds__(256) void cast_f32_bf16(const float* __restrict__ in, u16* __restrict__ o,
                                                     ll n4, float scale) {
  ll i = (ll)blockIdx.x * 256 + threadIdx.x;
  ll stride = (ll)gridDim.x * 256;
  for (; i < n4; i += stride) {
    float4 f = ((const float4*)in)[i];
    ushort4 u;
    u.x = f2bf(f.x * scale); u.y = f2bf(f.y * scale);
    u.z = f2bf(f.z * scale); u.w = f2bf(f.w * scale);
    ((ushort4*)o)[i] = u;
  }
}

// W_kv[:, 0:4096] (ld 8192) -> Wk bf16 [1024][4096]
__global__ __launch_bounds__(256) void cast_wk(const float* __restrict__ Wkv, u16* __restrict__ Wk) {
  ll i = (ll)blockIdx.x * 256 + threadIdx.x;
  ll stride = (ll)gridDim.x * 256;
  const ll total = 1024ll * 1024;  // float4 count
  for (; i < total; i += stride) {
    int row = (int)(i >> 10), c4 = (int)(i & 1023);
    float4 f = ((const float4*)(Wkv + (size_t)row * 8192))[c4];
    ushort4 u;
    u.x = f2bf(f.x); u.y = f2bf(f.y); u.z = f2bf(f.z); u.w = f2bf(f.w);
    ((ushort4*)(Wk + (size_t)row * 4096))[c4] = u;
  }
}

// out[c][r] = bf16(in[r][c0+c]); 32x32 LDS tile, grid (C/32, R/32)
__global__ __launch_bounds__(256) void transpose_cast(const float* __restrict__ in, int ldin, int c0,
                                                      u16* __restrict__ outp, int R, int C) {
  __shared__ float tile[32][33];
  int bc = blockIdx.x * 32;
  int br = blockIdx.y * 32;
  int tx = threadIdx.x & 31, ty = threadIdx.x >> 5;  // 32x8
#pragma unroll
  for (int j = 0; j < 32; j += 8)
    tile[ty + j][tx] = in[(size_t)(br + ty + j) * ldin + c0 + bc + tx];
  __syncthreads();
#pragma unroll
  for (int j = 0; j < 32; j += 8)
    outp[(size_t)(bc + ty + j) * R + br + tx] = f2bf(tile[tx][ty + j]);
}

extern "C" void kernel_launch(void* const* d_in, const int* in_sizes, int n_in,
                              void* d_out, int out_size, void* d_ws, size_t ws_size,
                              hipStream_t stream) {
  const float* vit = (const float*)d_in[0];  // [32,1024,1024]
  const float* qin = (const float*)d_in[1];  // [1,64,4096]
  const float* Wkv = (const float*)d_in[2];  // [1024,8192]
  const float* Wo  = (const float*)d_in[3];  // [4096,4096]
  float* out = (float*)d_out;                // [2048,4096]

  char* base = (char*)d_ws;
  size_t o = 0;
  auto carve = [&](size_t bytes) -> size_t {
    size_t p = o; o += (bytes + 255) & ~(size_t)255; return p;
  };
  size_t off_vit = carve(67108864);   // vit bf16 [32768,1024]
  size_t off_wk  = carve(8388608);    // Wk bf16 [1024,4096]
  size_t off_wvt = carve(8388608);    // Wv^T bf16 [4096,1024]
  size_t off_wot = carve(33554432);   // Wo^T bf16 [4096,4096]
  size_t off_q   = carve(524288);     // q*SCALE bf16 [64,4096]
  size_t off_ut  = carve(2097152);    // Ut bf16 [1024,1024]
  size_t off_ao  = carve(16777216);   // attn_out bf16 [2048,4096]
  size_t fixed = o;
  // per-batch-chunk buffers: St 2MB + P 2MB + vT 8MB (bf16) per b
  int CH = 32;
  while (CH > 1 && fixed + (size_t)CH * (2097408ull * 2 + 8388864ull) > ws_size) CH >>= 1;
  size_t off_st = carve((size_t)CH * 2097152);
  size_t off_p  = carve((size_t)CH * 2097152);
  size_t off_vt = carve((size_t)CH * 8388608);

  u16* vitb = (u16*)(base + off_vit);
  u16* wkb  = (u16*)(base + off_wk);
  u16* wvt  = (u16*)(base + off_wvt);
  u16* wot  = (u16*)(base + off_wot);
  u16* qb   = (u16*)(base + off_q);
  u16* ut   = (u16*)(base + off_ut);
  u16* aob  = (u16*)(base + off_ao);
  u16* stb  = (u16*)(base + off_st);
  u16* pb   = (u16*)(base + off_p);
  u16* vtb  = (u16*)(base + off_vt);

  // ---- prep casts ----
  cast_f32_bf16<<<4096, 256, 0, stream>>>(vit, vitb, 33554432ll / 4, 1.0f);
  cast_wk<<<2048, 256, 0, stream>>>(Wkv, wkb);
  transpose_cast<<<dim3(128, 32), 256, 0, stream>>>(Wkv, 8192, 4096, wvt, 1024, 4096);
  transpose_cast<<<dim3(128, 128), 256, 0, stream>>>(Wo, 4096, 0, wot, 4096, 4096);
  cast_f32_bf16<<<256, 256, 0, stream>>>(qin, qb, 262144ll / 4, 0.0625f);  // fold SCALE=1/16

  // ---- Ut[hq][vd] per head: M=64,N=1024,K=256, batch 16 heads ----
  gemm_bt<u16><<<dim3(8, 1, 16), 256, 0, stream>>>(
      qb, wkb, ut, 64, 1024, 256, 4096, 4096, 1024,
      16, 0, 256, 0, 256, 0, 65536);

  for (int cb = 0; cb < 32; cb += CH) {
    const u16* vb = vitb + (size_t)cb * 1048576;
    // St[b] = Ut @ vit_b^T : M=1024,N=1024,K=1024
    gemm_bt<u16><<<dim3(8, 8, CH), 256, 0, stream>>>(
        ut, vb, stb, 1024, 1024, 1024, 1024, 1024, 1024,
        1, 0, 0, 1048576, 0, 1048576, 0);
    // softmax rows -> P
    softmax_rows<<<CH * 1024, 256, 0, stream>>>(stb, pb);
    // vT[b] = Wv^T @ vit_b^T : M=4096,N=1024,K=1024
    gemm_bt<u16><<<dim3(8, 32, CH), 256, 0, stream>>>(
        wvt, vb, vtb, 4096, 1024, 1024, 1024, 1024, 1024,
        1, 0, 0, 1048576, 0, 4194304, 0);
    // attn_out[b,h] = P_bh @ vT_bh^T : M=64,N=256,K=1024, batch CH*16
    gemm_bt<u16><<<dim3(2, 1, CH * 16), 256, 0, stream>>>(
        pb, vtb, aob + (size_t)cb * 262144, 64, 256, 1024, 1024, 1024, 4096,
        16, 1048576, 65536, 4194304, 262144, 262144, 256);
  }

  // out = attn_out @ W_o : M=2048,N=4096,K=4096, fp32 out
  gemm_bt<float><<<dim3(32, 16, 1), 256, 0, stream>>>(
      aob, wot, out, 2048, 4096, 4096, 4096, 4096, 4096,
      1, 0, 0, 0, 0, 0, 0);
}

// Round 3
// 707.336 us; speedup vs baseline: 1.3675x; 1.3675x over previous
//
#include <hip/hip_runtime.h>
#include <hip/hip_bf16.h>
#include <stdint.h>

// PerceiverProjector on MI355X, restructured as bf16 MFMA GEMMs (R3 = R2 + prep_vit transpose fix):
//  Ut = (q*SCALE) @ W_k^T per head          [1024,1024]   0.5 GF
//  St[b] = Ut @ vit[b]^T                    [b][hq][n]   68.7 GF
//  P = softmax rows of St                   (n contiguous)
//  ctx[b] = P_b @ vit_b                     [b][hq][vd]  68.7 GF   (replaces vT, 275 GF)
//  attn_out[b,h] = ctx_bh @ Wv_h^T          [2048,4096]  17.2 GF
//  out = attn_out @ W_o                     fp32 out     68.7 GF

typedef unsigned short u16;
typedef long long ll;
typedef __attribute__((ext_vector_type(8))) __bf16 bf16x8;
typedef __attribute__((ext_vector_type(4))) float f32x4;

#define AS1 __attribute__((address_space(1)))
#define AS3 __attribute__((address_space(3)))

__device__ __forceinline__ u16 f2bf(float f) {
  unsigned u = __builtin_bit_cast(unsigned, f);
  return (u16)((u + 0x7FFFu + ((u >> 16) & 1u)) >> 16);  // RNE
}
__device__ __forceinline__ float bf2f(u16 b) {
  return __builtin_bit_cast(float, ((unsigned)b) << 16);
}
__device__ __forceinline__ void st_c(float* p, float v) { *p = v; }
__device__ __forceinline__ void st_c(u16* p, float v) { *p = f2bf(v); }

// async global->LDS, 16B per lane; LDS dest is wave-uniform base (+lane*16 HW-applied)
__device__ __forceinline__ void gload16(const u16* g, u16* l) {
  __builtin_amdgcn_global_load_lds((AS1 void*)(uintptr_t)g,
                                   (AS3 void*)(unsigned)(uintptr_t)l, 16, 0, 0);
}

// C[m][n] = sum_k A[m][k] * Bt[n][k]; 128x128 tile, BK=64, 4 waves (2x2), m97 structure.
// batch z -> (b1 = z/nb2, b2 = z%nb2); strides in elements.
template <typename CT>
__global__ __launch_bounds__(256, 2) void gemm_bt(
    const u16* __restrict__ A, const u16* __restrict__ Bt, CT* __restrict__ C,
    int M, int N, int K, int lda, int ldb, int ldc, int nb2,
    ll sA1, ll sA2, ll sB1, ll sB2, ll sC1, ll sC2)
{
  __shared__ __align__(16) u16 As[128 * 64];
  __shared__ __align__(16) u16 Bs[128 * 64];

  const int z = blockIdx.z;
  const int b1 = z / nb2, b2 = z - b1 * nb2;
  A += b1 * sA1 + b2 * sA2;
  Bt += b1 * sB1 + b2 * sB2;
  C += b1 * sC1 + b2 * sC2;

  const int m0 = blockIdx.y * 128;
  const int n0 = blockIdx.x * 128;
  const int tid = threadIdx.x;
  const int lane = tid & 63;
  const int wave = tid >> 6;

  const int srow = lane >> 3;        // 0..7 within an 8-row 1KB chunk
  const int scol = (lane & 7) << 3;  // bf16 col, 16B per lane
  const int wr = (wave >> 1) << 6;   // wave row offset 0/64
  const int wc = (wave & 1) << 6;    // wave col offset 0/64
  const int lrow = lane & 15;
  const int lk = (lane >> 4) << 3;   // per-lane k offset 0/8/16/24

  f32x4 acc[4][4];
#pragma unroll
  for (int i = 0; i < 4; ++i)
#pragma unroll
    for (int j = 0; j < 4; ++j) { f32x4 zz = {0.f, 0.f, 0.f, 0.f}; acc[i][j] = zz; }

  for (int k0 = 0; k0 < K; k0 += 64) {
#pragma unroll
    for (int i = 0; i < 4; ++i) {               // stage A tile 128x64 (16KB)
      int chunk = (i << 2) + wave;
      int row = (chunk << 3) + srow;
      int gr = m0 + row; gr = gr < M ? gr : M - 1;   // clamp (stores guarded)
      gload16(A + (size_t)gr * lda + k0 + scol, &As[chunk << 9]);
    }
#pragma unroll
    for (int i = 0; i < 4; ++i) {               // stage Bt tile 128x64
      int chunk = (i << 2) + wave;
      int row = (chunk << 3) + srow;
      int gc = n0 + row; gc = gc < N ? gc : N - 1;
      gload16(Bt + (size_t)gc * ldb + k0 + scol, &Bs[chunk << 9]);
    }
    __syncthreads();  // compiler drains vmcnt before barrier
#pragma unroll
    for (int ks = 0; ks < 64; ks += 32) {
      bf16x8 af[4], bfr[4];
#pragma unroll
      for (int mi = 0; mi < 4; ++mi)
        af[mi] = *(const bf16x8*)&As[((wr + (mi << 4) + lrow) << 6) + ks + lk];
#pragma unroll
      for (int ni = 0; ni < 4; ++ni)
        bfr[ni] = *(const bf16x8*)&Bs[((wc + (ni << 4) + lrow) << 6) + ks + lk];
#pragma unroll
      for (int mi = 0; mi < 4; ++mi)
#pragma unroll
        for (int ni = 0; ni < 4; ++ni)
          acc[mi][ni] = __builtin_amdgcn_mfma_f32_16x16x32_bf16(af[mi], bfr[ni], acc[mi][ni], 0, 0, 0);
    }
    __syncthreads();
  }

  const int rbase = m0 + wr + ((lane >> 4) << 2);
  const int cbase = n0 + wc + lrow;
#pragma unroll
  for (int mi = 0; mi < 4; ++mi)
#pragma unroll
    for (int r = 0; r < 4; ++r) {
      int row = rbase + (mi << 4) + r;
      if (row < M) {
#pragma unroll
        for (int ni = 0; ni < 4; ++ni) {
          int col = cbase + (ni << 4);
          if (col < N) st_c(&C[(size_t)row * ldc + col], acc[mi][ni][r]);
        }
      }
    }
}

// one block per row of 1024 bf16 logits -> normalized bf16 probs
__global__ __launch_bounds__(256) void softmax_rows(const u16* __restrict__ S, u16* __restrict__ P) {
  __shared__ float red[8];
  size_t row = blockIdx.x;
  const u16* s = S + row * 1024;
  u16* p = P + row * 1024;
  int t = threadIdx.x;
  ushort4 ld = ((const ushort4*)s)[t];
  float v0 = bf2f(ld.x), v1 = bf2f(ld.y), v2 = bf2f(ld.z), v3 = bf2f(ld.w);
  float m = fmaxf(fmaxf(v0, v1), fmaxf(v2, v3));
#pragma unroll
  for (int o = 32; o; o >>= 1) m = fmaxf(m, __shfl_xor(m, o));
  if ((t & 63) == 0) red[t >> 6] = m;
  __syncthreads();
  m = fmaxf(fmaxf(red[0], red[1]), fmaxf(red[2], red[3]));
  float e0 = __expf(v0 - m), e1 = __expf(v1 - m), e2 = __expf(v2 - m), e3 = __expf(v3 - m);
  float sum = (e0 + e1) + (e2 + e3);
#pragma unroll
  for (int o = 32; o; o >>= 1) sum += __shfl_xor(sum, o);
  if ((t & 63) == 0) red[4 + (t >> 6)] = sum;
  __syncthreads();
  sum = (red[4] + red[5]) + (red[6] + red[7]);
  float rs = 1.0f / (sum + 1e-9f);
  ushort4 o4;
  o4.x = f2bf(e0 * rs); o4.y = f2bf(e1 * rs); o4.z = f2bf(e2 * rs); o4.w = f2bf(e3 * rs);
  ((ushort4*)p)[t] = o4;
}

// contiguous fp32 -> bf16 cast (xscale), float4 vectorized, grid-stride
__global__ __launch_bounds__(256) void cast_f32_bf16(const float* __restrict__ in, u16* __restrict__ o,
                                                     ll n4, float scale) {
  ll i = (ll)blockIdx.x * 256 + threadIdx.x;
  ll stride = (ll)gridDim.x * 256;
  for (; i < n4; i += stride) {
    float4 f = ((const float4*)in)[i];
    ushort4 u;
    u.x = f2bf(f.x * scale); u.y = f2bf(f.y * scale);
    u.z = f2bf(f.z * scale); u.w = f2bf(f.w * scale);
    ((ushort4*)o)[i] = u;
  }
}

// W_kv[:, 0:4096] (ld 8192) -> Wk bf16 [1024][4096]
__global__ __launch_bounds__(256) void cast_wk(const float* __restrict__ Wkv, u16* __restrict__ Wk) {
  ll i = (ll)blockIdx.x * 256 + threadIdx.x;
  ll stride = (ll)gridDim.x * 256;
  const ll total = 1024ll * 1024;  // float4 count
  for (; i < total; i += stride) {
    int row = (int)(i >> 10), c4 = (int)(i & 1023);
    float4 f = ((const float4*)(Wkv + (size_t)row * 8192))[c4];
    ushort4 u;
    u.x = f2bf(f.x); u.y = f2bf(f.y); u.z = f2bf(f.z); u.w = f2bf(f.w);
    ((ushort4*)(Wk + (size_t)row * 4096))[c4] = u;
  }
}

// out[c][r] = bf16(in[r][c0+c]); 32x32 LDS tile, grid (C/32, R/32)
__global__ __launch_bounds__(256) void transpose_cast(const float* __restrict__ in, int ldin, int c0,
                                                      u16* __restrict__ outp, int R, int C) {
  __shared__ float tile[32][33];
  int bc = blockIdx.x * 32;
  int br = blockIdx.y * 32;
  int tx = threadIdx.x & 31, ty = threadIdx.x >> 5;  // 32x8
#pragma unroll
  for (int j = 0; j < 32; j += 8)
    tile[ty + j][tx] = in[(size_t)(br + ty + j) * ldin + c0 + bc + tx];
  __syncthreads();
#pragma unroll
  for (int j = 0; j < 32; j += 8)
    outp[(size_t)(bc + ty + j) * R + br + tx] = f2bf(tile[tx][ty + j]);
}

// vit fp32 [32][1024][1024] -> vitb bf16 row-major AND vitT bf16 transposed, one pass.
// Tile: 32 n-rows x 64 vd-cols. FIX (R3): transpose-store now uses a bijective
// (vd, n-pair) map — thread -> p = tx&15 (n = br+2p), vdl = ty*2+(tx>>4) + {0,16,32,48}.
// Previous version indexed tile[tx*2][..] with tx*2 up to 62 >= 32 rows (OOB LDS read
// + cross-block global write race).
__global__ __launch_bounds__(256) void prep_vit(const float* __restrict__ in,
                                                u16* __restrict__ rm, u16* __restrict__ tr) {
  __shared__ float tile[32][65];
  int b = blockIdx.z;
  const float* inb = in + (size_t)b * 1048576;
  u16* rmb = rm + (size_t)b * 1048576;
  u16* trb = tr + (size_t)b * 1048576;
  int bc = blockIdx.x * 64, br = blockIdx.y * 32;
  int tx = threadIdx.x & 31, ty = threadIdx.x >> 5;  // 32x8
#pragma unroll
  for (int j = 0; j < 32; j += 8) {
    float2 v = *(const float2*)&inb[(size_t)(br + ty + j) * 1024 + bc + tx * 2];
    tile[ty + j][tx * 2] = v.x;
    tile[ty + j][tx * 2 + 1] = v.y;
    ushort2 u; u.x = f2bf(v.x); u.y = f2bf(v.y);
    *(ushort2*)&rmb[(size_t)(br + ty + j) * 1024 + bc + tx * 2] = u;
  }
  __syncthreads();
  const int p = tx & 15;                 // n-pair: n = br + 2p, 2p+1  (in [0,32))
  const int vbase = ty * 2 + (tx >> 4);  // 0..15
#pragma unroll
  for (int j = 0; j < 64; j += 16) {
    int vdl = vbase + j;                 // 0..63
    ushort2 u;
    u.x = f2bf(tile[2 * p][vdl]);
    u.y = f2bf(tile[2 * p + 1][vdl]);
    *(ushort2*)&trb[(size_t)(bc + vdl) * 1024 + br + 2 * p] = u;
  }
}

extern "C" void kernel_launch(void* const* d_in, const int* in_sizes, int n_in,
                              void* d_out, int out_size, void* d_ws, size_t ws_size,
                              hipStream_t stream) {
  const float* vit = (const float*)d_in[0];  // [32,1024,1024]
  const float* qin = (const float*)d_in[1];  // [1,64,4096]
  const float* Wkv = (const float*)d_in[2];  // [1024,8192]
  const float* Wo  = (const float*)d_in[3];  // [4096,4096]
  float* out = (float*)d_out;                // [2048,4096]

  char* base = (char*)d_ws;
  size_t o = 0;
  auto carve = [&](size_t bytes) -> size_t {
    size_t p = o; o += (bytes + 255) & ~(size_t)255; return p;
  };
  size_t off_vit  = carve(67108864);   // vitb bf16 [32][1024][1024]
  size_t off_vitT = carve(67108864);   // vitT bf16 [32][1024 vd][1024 n]
  size_t off_wk   = carve(8388608);    // Wk bf16 [1024,4096]
  size_t off_wvt  = carve(8388608);    // Wv^T bf16 [4096,1024]
  size_t off_wot  = carve(33554432);   // Wo^T bf16 [4096,4096]
  size_t off_q    = carve(524288);     // q*SCALE bf16 [64,4096]
  size_t off_ut   = carve(2097152);    // Ut bf16 [1024,1024] rows hq=h*64+q
  size_t off_ao   = carve(16777216);   // attn_out bf16 [2048,4096]
  size_t fixed = o;
  // per-batch-chunk buffers: St 2MB + P 2MB + ctx 2MB (bf16) per b
  int CH = 32;
  while (CH > 1 && fixed + (size_t)CH * (3ull * 2097408ull) > ws_size) CH >>= 1;
  size_t off_st  = carve((size_t)CH * 2097152);
  size_t off_p   = carve((size_t)CH * 2097152);
  size_t off_ctx = carve((size_t)CH * 2097152);

  u16* vitb = (u16*)(base + off_vit);
  u16* vitT = (u16*)(base + off_vitT);
  u16* wkb  = (u16*)(base + off_wk);
  u16* wvt  = (u16*)(base + off_wvt);
  u16* wot  = (u16*)(base + off_wot);
  u16* qb   = (u16*)(base + off_q);
  u16* ut   = (u16*)(base + off_ut);
  u16* aob  = (u16*)(base + off_ao);
  u16* stb  = (u16*)(base + off_st);
  u16* pb   = (u16*)(base + off_p);
  u16* ctxb = (u16*)(base + off_ctx);

  // ---- prep casts ----
  prep_vit<<<dim3(16, 32, 32), 256, 0, stream>>>(vit, vitb, vitT);
  cast_wk<<<2048, 256, 0, stream>>>(Wkv, wkb);
  transpose_cast<<<dim3(128, 32), 256, 0, stream>>>(Wkv, 8192, 4096, wvt, 1024, 4096);
  transpose_cast<<<dim3(128, 128), 256, 0, stream>>>(Wo, 4096, 0, wot, 4096, 4096);
  cast_f32_bf16<<<256, 256, 0, stream>>>(qin, qb, 262144ll / 4, 0.0625f);  // fold SCALE=1/16

  // ---- Ut[hq][vd] per head: M=64,N=1024,K=256, batch 16 heads ----
  gemm_bt<u16><<<dim3(8, 1, 16), 256, 0, stream>>>(
      qb, wkb, ut, 64, 1024, 256, 4096, 4096, 1024,
      16, 0, 256, 0, 256, 0, 65536);

  for (int cb = 0; cb < 32; cb += CH) {
    const u16* vb  = vitb + (size_t)cb * 1048576;
    const u16* vtb = vitT + (size_t)cb * 1048576;
    // St[b] = Ut @ vit_b^T : M=1024,N=1024,K=1024
    gemm_bt<u16><<<dim3(8, 8, CH), 256, 0, stream>>>(
        ut, vb, stb, 1024, 1024, 1024, 1024, 1024, 1024,
        1, 0, 0, 1048576, 0, 1048576, 0);
    // softmax rows -> P
    softmax_rows<<<CH * 1024, 256, 0, stream>>>(stb, pb);
    // ctx[b] = P_b @ vit_b  (Bt = vitT_b) : M=1024,N=1024,K=1024
    gemm_bt<u16><<<dim3(8, 8, CH), 256, 0, stream>>>(
        pb, vtb, ctxb, 1024, 1024, 1024, 1024, 1024, 1024,
        1, 1048576, 0, 1048576, 0, 1048576, 0);
    // attn_out[b,h] = ctx_bh @ Wv_h^T : M=64,N=256,K=1024, batch CH*16
    gemm_bt<u16><<<dim3(2, 1, CH * 16), 256, 0, stream>>>(
        ctxb, wvt, aob + (size_t)cb * 262144, 64, 256, 1024, 1024, 1024, 4096,
        16, 1048576, 65536, 0, 262144, 262144, 256);
  }

  // out = attn_out @ W_o : M=2048,N=4096,K=4096, fp32 out
  gemm_bt<float><<<dim3(32, 16, 1), 256, 0, stream>>>(
      aob, wot, out, 2048, 4096, 4096, 4096, 4096, 4096,
      1, 0, 0, 0, 0, 0, 0);
}

// Round 5
// 673.734 us; speedup vs baseline: 1.4357x; 1.0499x over previous
//
#include <hip/hip_runtime.h>
#include <hip/hip_bf16.h>
#include <stdint.h>

// PerceiverProjector on MI355X, restructured as bf16 MFMA GEMMs (R4 = R3 + occupancy 2->4 blocks/CU):
//  Ut = (q*SCALE) @ W_k^T per head          [1024,1024]   0.5 GF
//  St[b] = Ut @ vit[b]^T                    [b][hq][n]   68.7 GF
//  P = softmax rows of St                   (n contiguous)
//  ctx[b] = P_b @ vit_b                     [b][hq][vd]  68.7 GF
//  attn_out[b,h] = ctx_bh @ Wv_h^T          [2048,4096]  17.2 GF
//  out = attn_out @ W_o                     fp32 out     68.7 GF

typedef unsigned short u16;
typedef long long ll;
typedef __attribute__((ext_vector_type(8))) __bf16 bf16x8;
typedef __attribute__((ext_vector_type(4))) float f32x4;

#define AS1 __attribute__((address_space(1)))
#define AS3 __attribute__((address_space(3)))

__device__ __forceinline__ u16 f2bf(float f) {
  unsigned u = __builtin_bit_cast(unsigned, f);
  return (u16)((u + 0x7FFFu + ((u >> 16) & 1u)) >> 16);  // RNE
}
__device__ __forceinline__ float bf2f(u16 b) {
  return __builtin_bit_cast(float, ((unsigned)b) << 16);
}
__device__ __forceinline__ void st_c(float* p, float v) { *p = v; }
__device__ __forceinline__ void st_c(u16* p, float v) { *p = f2bf(v); }

// async global->LDS, 16B per lane; LDS dest is wave-uniform base (+lane*16 HW-applied)
__device__ __forceinline__ void gload16(const u16* g, u16* l) {
  __builtin_amdgcn_global_load_lds((AS1 void*)(uintptr_t)g,
                                   (AS3 void*)(unsigned)(uintptr_t)l, 16, 0, 0);
}

// C[m][n] = sum_k A[m][k] * Bt[n][k]; 128x128 tile, BK=64, 4 waves (2x2), m97 structure.
// __launch_bounds__(256,4): 4 blocks/CU (LDS 32KB ea -> 128/160KB; VGPR 76 <= 128 cap).
// R3's (256,2) left only 2 resident blocks -> barrier drains unhidden (Occ 21%, MfmaUtil 21%).
template <typename CT>
__global__ __launch_bounds__(256, 4) void gemm_bt(
    const u16* __restrict__ A, const u16* __restrict__ Bt, CT* __restrict__ C,
    int M, int N, int K, int lda, int ldb, int ldc, int nb2,
    ll sA1, ll sA2, ll sB1, ll sB2, ll sC1, ll sC2)
{
  __shared__ __align__(16) u16 As[128 * 64];
  __shared__ __align__(16) u16 Bs[128 * 64];

  const int z = blockIdx.z;
  const int b1 = z / nb2, b2 = z - b1 * nb2;
  A += b1 * sA1 + b2 * sA2;
  Bt += b1 * sB1 + b2 * sB2;
  C += b1 * sC1 + b2 * sC2;

  const int m0 = blockIdx.y * 128;
  const int n0 = blockIdx.x * 128;
  const int tid = threadIdx.x;
  const int lane = tid & 63;
  const int wave = tid >> 6;

  const int srow = lane >> 3;        // 0..7 within an 8-row 1KB chunk
  const int scol = (lane & 7) << 3;  // bf16 col, 16B per lane
  const int wr = (wave >> 1) << 6;   // wave row offset 0/64
  const int wc = (wave & 1) << 6;    // wave col offset 0/64
  const int lrow = lane & 15;
  const int lk = (lane >> 4) << 3;   // per-lane k offset 0/8/16/24

  f32x4 acc[4][4];
#pragma unroll
  for (int i = 0; i < 4; ++i)
#pragma unroll
    for (int j = 0; j < 4; ++j) { f32x4 zz = {0.f, 0.f, 0.f, 0.f}; acc[i][j] = zz; }

  for (int k0 = 0; k0 < K; k0 += 64) {
#pragma unroll
    for (int i = 0; i < 4; ++i) {               // stage A tile 128x64 (16KB)
      int chunk = (i << 2) + wave;
      int row = (chunk << 3) + srow;
      int gr = m0 + row; gr = gr < M ? gr : M - 1;   // clamp (stores guarded)
      gload16(A + (size_t)gr * lda + k0 + scol, &As[chunk << 9]);
    }
#pragma unroll
    for (int i = 0; i < 4; ++i) {               // stage Bt tile 128x64
      int chunk = (i << 2) + wave;
      int row = (chunk << 3) + srow;
      int gc = n0 + row; gc = gc < N ? gc : N - 1;
      gload16(Bt + (size_t)gc * ldb + k0 + scol, &Bs[chunk << 9]);
    }
    __syncthreads();  // compiler drains vmcnt before barrier
#pragma unroll
    for (int ks = 0; ks < 64; ks += 32) {
      bf16x8 af[4], bfr[4];
#pragma unroll
      for (int mi = 0; mi < 4; ++mi)
        af[mi] = *(const bf16x8*)&As[((wr + (mi << 4) + lrow) << 6) + ks + lk];
#pragma unroll
      for (int ni = 0; ni < 4; ++ni)
        bfr[ni] = *(const bf16x8*)&Bs[((wc + (ni << 4) + lrow) << 6) + ks + lk];
#pragma unroll
      for (int mi = 0; mi < 4; ++mi)
#pragma unroll
        for (int ni = 0; ni < 4; ++ni)
          acc[mi][ni] = __builtin_amdgcn_mfma_f32_16x16x32_bf16(af[mi], bfr[ni], acc[mi][ni], 0, 0, 0);
    }
    __syncthreads();
  }

  const int rbase = m0 + wr + ((lane >> 4) << 2);
  const int cbase = n0 + wc + lrow;
#pragma unroll
  for (int mi = 0; mi < 4; ++mi)
#pragma unroll
    for (int r = 0; r < 4; ++r) {
      int row = rbase + (mi << 4) + r;
      if (row < M) {
#pragma unroll
        for (int ni = 0; ni < 4; ++ni) {
          int col = cbase + (ni << 4);
          if (col < N) st_c(&C[(size_t)row * ldc + col], acc[mi][ni][r]);
        }
      }
    }
}

// one block per row of 1024 bf16 logits -> normalized bf16 probs
__global__ __launch_bounds__(256) void softmax_rows(const u16* __restrict__ S, u16* __restrict__ P) {
  __shared__ float red[8];
  size_t row = blockIdx.x;
  const u16* s = S + row * 1024;
  u16* p = P + row * 1024;
  int t = threadIdx.x;
  ushort4 ld = ((const ushort4*)s)[t];
  float v0 = bf2f(ld.x), v1 = bf2f(ld.y), v2 = bf2f(ld.z), v3 = bf2f(ld.w);
  float m = fmaxf(fmaxf(v0, v1), fmaxf(v2, v3));
#pragma unroll
  for (int o = 32; o; o >>= 1) m = fmaxf(m, __shfl_xor(m, o));
  if ((t & 63) == 0) red[t >> 6] = m;
  __syncthreads();
  m = fmaxf(fmaxf(red[0], red[1]), fmaxf(red[2], red[3]));
  float e0 = __expf(v0 - m), e1 = __expf(v1 - m), e2 = __expf(v2 - m), e3 = __expf(v3 - m);
  float sum = (e0 + e1) + (e2 + e3);
#pragma unroll
  for (int o = 32; o; o >>= 1) sum += __shfl_xor(sum, o);
  if ((t & 63) == 0) red[4 + (t >> 6)] = sum;
  __syncthreads();
  sum = (red[4] + red[5]) + (red[6] + red[7]);
  float rs = 1.0f / (sum + 1e-9f);
  ushort4 o4;
  o4.x = f2bf(e0 * rs); o4.y = f2bf(e1 * rs); o4.z = f2bf(e2 * rs); o4.w = f2bf(e3 * rs);
  ((ushort4*)p)[t] = o4;
}

// contiguous fp32 -> bf16 cast (xscale), float4 vectorized, grid-stride
__global__ __launch_bounds__(256) void cast_f32_bf16(const float* __restrict__ in, u16* __restrict__ o,
                                                     ll n4, float scale) {
  ll i = (ll)blockIdx.x * 256 + threadIdx.x;
  ll stride = (ll)gridDim.x * 256;
  for (; i < n4; i += stride) {
    float4 f = ((const float4*)in)[i];
    ushort4 u;
    u.x = f2bf(f.x * scale); u.y = f2bf(f.y * scale);
    u.z = f2bf(f.z * scale); u.w = f2bf(f.w * scale);
    ((ushort4*)o)[i] = u;
  }
}

// W_kv[:, 0:4096] (ld 8192) -> Wk bf16 [1024][4096]
__global__ __launch_bounds__(256) void cast_wk(const float* __restrict__ Wkv, u16* __restrict__ Wk) {
  ll i = (ll)blockIdx.x * 256 + threadIdx.x;
  ll stride = (ll)gridDim.x * 256;
  const ll total = 1024ll * 1024;  // float4 count
  for (; i < total; i += stride) {
    int row = (int)(i >> 10), c4 = (int)(i & 1023);
    float4 f = ((const float4*)(Wkv + (size_t)row * 8192))[c4];
    ushort4 u;
    u.x = f2bf(f.x); u.y = f2bf(f.y); u.z = f2bf(f.z); u.w = f2bf(f.w);
    ((ushort4*)(Wk + (size_t)row * 4096))[c4] = u;
  }
}

// out[c][r] = bf16(in[r][c0+c]); 32x32 LDS tile, grid (C/32, R/32)
__global__ __launch_bounds__(256) void transpose_cast(const float* __restrict__ in, int ldin, int c0,
                                                      u16* __restrict__ outp, int R, int C) {
  __shared__ float tile[32][33];
  int bc = blockIdx.x * 32;
  int br = blockIdx.y * 32;
  int tx = threadIdx.x & 31, ty = threadIdx.x >> 5;  // 32x8
#pragma unroll
  for (int j = 0; j < 32; j += 8)
    tile[ty + j][tx] = in[(size_t)(br + ty + j) * ldin + c0 + bc + tx];
  __syncthreads();
#pragma unroll
  for (int j = 0; j < 32; j += 8)
    outp[(size_t)(bc + ty + j) * R + br + tx] = f2bf(tile[tx][ty + j]);
}

// vit fp32 [32][1024][1024] -> vitb bf16 row-major AND vitT bf16 transposed, one pass.
// Tile: 32 n-rows x 64 vd-cols; transpose-store uses bijective (vd, n-pair) map.
__global__ __launch_bounds__(256) void prep_vit(const float* __restrict__ in,
                                                u16* __restrict__ rm, u16* __restrict__ tr) {
  __shared__ float tile[32][65];
  int b = blockIdx.z;
  const float* inb = in + (size_t)b * 1048576;
  u16* rmb = rm + (size_t)b * 1048576;
  u16* trb = tr + (size_t)b * 1048576;
  int bc = blockIdx.x * 64, br = blockIdx.y * 32;
  int tx = threadIdx.x & 31, ty = threadIdx.x >> 5;  // 32x8
#pragma unroll
  for (int j = 0; j < 32; j += 8) {
    float2 v = *(const float2*)&inb[(size_t)(br + ty + j) * 1024 + bc + tx * 2];
    tile[ty + j][tx * 2] = v.x;
    tile[ty + j][tx * 2 + 1] = v.y;
    ushort2 u; u.x = f2bf(v.x); u.y = f2bf(v.y);
    *(ushort2*)&rmb[(size_t)(br + ty + j) * 1024 + bc + tx * 2] = u;
  }
  __syncthreads();
  const int p = tx & 15;                 // n-pair: n = br + 2p, 2p+1  (in [0,32))
  const int vbase = ty * 2 + (tx >> 4);  // 0..15
#pragma unroll
  for (int j = 0; j < 64; j += 16) {
    int vdl = vbase + j;                 // 0..63
    ushort2 u;
    u.x = f2bf(tile[2 * p][vdl]);
    u.y = f2bf(tile[2 * p + 1][vdl]);
    *(ushort2*)&trb[(size_t)(bc + vdl) * 1024 + br + 2 * p] = u;
  }
}

extern "C" void kernel_launch(void* const* d_in, const int* in_sizes, int n_in,
                              void* d_out, int out_size, void* d_ws, size_t ws_size,
                              hipStream_t stream) {
  const float* vit = (const float*)d_in[0];  // [32,1024,1024]
  const float* qin = (const float*)d_in[1];  // [1,64,4096]
  const float* Wkv = (const float*)d_in[2];  // [1024,8192]
  const float* Wo  = (const float*)d_in[3];  // [4096,4096]
  float* out = (float*)d_out;                // [2048,4096]

  char* base = (char*)d_ws;
  size_t o = 0;
  auto carve = [&](size_t bytes) -> size_t {
    size_t p = o; o += (bytes + 255) & ~(size_t)255; return p;
  };
  size_t off_vit  = carve(67108864);   // vitb bf16 [32][1024][1024]
  size_t off_vitT = carve(67108864);   // vitT bf16 [32][1024 vd][1024 n]
  size_t off_wk   = carve(8388608);    // Wk bf16 [1024,4096]
  size_t off_wvt  = carve(8388608);    // Wv^T bf16 [4096,1024]
  size_t off_wot  = carve(33554432);   // Wo^T bf16 [4096,4096]
  size_t off_q    = carve(524288);     // q*SCALE bf16 [64,4096]
  size_t off_ut   = carve(2097152);    // Ut bf16 [1024,1024] rows hq=h*64+q
  size_t off_ao   = carve(16777216);   // attn_out bf16 [2048,4096]
  size_t fixed = o;
  // per-batch-chunk buffers: St 2MB + P 2MB + ctx 2MB (bf16) per b
  int CH = 32;
  while (CH > 1 && fixed + (size_t)CH * (3ull * 2097408ull) > ws_size) CH >>= 1;
  size_t off_st  = carve((size_t)CH * 2097152);
  size_t off_p   = carve((size_t)CH * 2097152);
  size_t off_ctx = carve((size_t)CH * 2097152);

  u16* vitb = (u16*)(base + off_vit);
  u16* vitT = (u16*)(base + off_vitT);
  u16* wkb  = (u16*)(base + off_wk);
  u16* wvt  = (u16*)(base + off_wvt);
  u16* wot  = (u16*)(base + off_wot);
  u16* qb   = (u16*)(base + off_q);
  u16* ut   = (u16*)(base + off_ut);
  u16* aob  = (u16*)(base + off_ao);
  u16* stb  = (u16*)(base + off_st);
  u16* pb   = (u16*)(base + off_p);
  u16* ctxb = (u16*)(base + off_ctx);

  // ---- prep casts ----
  prep_vit<<<dim3(16, 32, 32), 256, 0, stream>>>(vit, vitb, vitT);
  cast_wk<<<2048, 256, 0, stream>>>(Wkv, wkb);
  transpose_cast<<<dim3(128, 32), 256, 0, stream>>>(Wkv, 8192, 4096, wvt, 1024, 4096);
  transpose_cast<<<dim3(128, 128), 256, 0, stream>>>(Wo, 4096, 0, wot, 4096, 4096);
  cast_f32_bf16<<<256, 256, 0, stream>>>(qin, qb, 262144ll / 4, 0.0625f);  // fold SCALE=1/16

  // ---- Ut[hq][vd] per head: M=64,N=1024,K=256, batch 16 heads ----
  gemm_bt<u16><<<dim3(8, 1, 16), 256, 0, stream>>>(
      qb, wkb, ut, 64, 1024, 256, 4096, 4096, 1024,
      16, 0, 256, 0, 256, 0, 65536);

  for (int cb = 0; cb < 32; cb += CH) {
    const u16* vb  = vitb + (size_t)cb * 1048576;
    const u16* vtb = vitT + (size_t)cb * 1048576;
    // St[b] = Ut @ vit_b^T : M=1024,N=1024,K=1024
    gemm_bt<u16><<<dim3(8, 8, CH), 256, 0, stream>>>(
        ut, vb, stb, 1024, 1024, 1024, 1024, 1024, 1024,
        1, 0, 0, 1048576, 0, 1048576, 0);
    // softmax rows -> P
    softmax_rows<<<CH * 1024, 256, 0, stream>>>(stb, pb);
    // ctx[b] = P_b @ vit_b  (Bt = vitT_b) : M=1024,N=1024,K=1024
    gemm_bt<u16><<<dim3(8, 8, CH), 256, 0, stream>>>(
        pb, vtb, ctxb, 1024, 1024, 1024, 1024, 1024, 1024,
        1, 1048576, 0, 1048576, 0, 1048576, 0);
    // attn_out[b,h] = ctx_bh @ Wv_h^T : M=64,N=256,K=1024, batch CH*16
    gemm_bt<u16><<<dim3(2, 1, CH * 16), 256, 0, stream>>>(
        ctxb, wvt, aob + (size_t)cb * 262144, 64, 256, 1024, 1024, 1024, 4096,
        16, 1048576, 65536, 0, 262144, 262144, 256);
  }

  // out = attn_out @ W_o : M=2048,N=4096,K=4096, fp32 out
  gemm_bt<float><<<dim3(32, 16, 1), 256, 0, stream>>>(
      aob, wot, out, 2048, 4096, 4096, 4096, 4096, 4096,
      1, 0, 0, 0, 0, 0, 0);
}